// Round 8
// baseline (1879.786 us; speedup 1.0000x reference)
//
#include <hip/hip_runtime.h>
#include <math.h>

// Problem constants
constexpr int Bn  = 2;
constexpr int MQn = 1024;
constexpr int D0 = 64, D1 = 32, D2 = 16, D3 = 8;

// Output layout (floats): x [2,128,8,8,8] = 131072, q [1,2,2] = 4, k [3,2] = 6
constexpr int OUT_X = 0;
constexpr int OUT_Q = 131072;
constexpr int OUT_K = 131076;

// Workspace layout (floats). Zero-initialized span first (single memset).
constexpr size_t OFF_CNT   = 0;
constexpr size_t OFF_ZERO  = 8;                    // 32B zero block for DMA padding
constexpr size_t OFF_T2CL  = 16;                   // CL fp32 2*16^3*64
constexpr size_t OFF_T3CL  = OFF_T2CL + 524288;    // CL fp32 2*8^3*96
constexpr size_t OFF_D1CL  = OFF_T3CL + 98304;     // CL fp32 2*32^3*32
constexpr size_t OFF_D2CL  = OFF_D1CL + 2097152;
constexpr size_t OFF_D3CL  = OFF_D2CL + 524288;
constexpr size_t ZERO_END  = OFF_D3CL + 98304;     // 3342352
// non-zeroed region
constexpr size_t OFF_SCALE = ZERO_END;             // 8
constexpr size_t OFF_M1    = OFF_SCALE + 8;        // 2*32^3
constexpr size_t OFF_M2    = OFF_M1 + 65536;
constexpr size_t OFF_M3    = OFF_M2 + 8192;
constexpr size_t OFF_T1CL  = OFF_M3 + 1024;        // CL fp32 2*32^3*32
constexpr size_t OFF_XCL   = OFF_T1CL + 2097152;   // CL bf16 2*64^3*8 sh
constexpr size_t OFF_Y1C   = OFF_XCL + 2097152;    // CL bf16 2*32^3*32 sh
constexpr size_t OFF_SQ1   = OFF_Y1C + 1048576;    // CL bf16
constexpr size_t OFF_Y2C   = OFF_SQ1 + 1048576;    // CL bf16 2*16^3*64 sh
constexpr size_t OFF_SQ2   = OFF_Y2C + 262144;
constexpr size_t OFF_Y3C   = OFF_SQ2 + 262144;     // CL bf16 2*8^3*96 sh
constexpr size_t OFF_SQ3   = OFF_Y3C + 49152;
// bf16 MFMA weights [cs][nch][tap][n32][kc2][8]
constexpr size_t OFF_WC1   = OFF_SQ3 + 49152;      // 64000 sh
constexpr size_t OFF_WG1   = OFF_WC1 + 32000;      // 128000 sh
constexpr size_t OFF_WC2   = OFF_WG1 + 64000;      // 256000 sh
constexpr size_t OFF_WG2   = OFF_WC2 + 128000;     // 512000 sh
constexpr size_t OFF_WC3   = OFF_WG2 + 256000;     // 768000 sh
constexpr size_t OFF_WG3   = OFF_WC3 + 384000;     // 1152000 sh
constexpr size_t OFF_WC4   = OFF_WG3 + 576000;     // 1536000 sh
// end ~12.5M floats (~50 MB)

typedef float v4f __attribute__((ext_vector_type(4)));
typedef __attribute__((ext_vector_type(4)))  short bf16x4v;
typedef __attribute__((ext_vector_type(8)))  short bf16x8v;
typedef __attribute__((ext_vector_type(16))) float f32x16v;

__device__ __forceinline__ void async_copy16(const float* g, float* l) {
    __builtin_amdgcn_global_load_lds(
        (const __attribute__((address_space(1))) void*)g,
        (__attribute__((address_space(3))) void*)l, 16, 0, 0);
}
__device__ __forceinline__ unsigned short f2bf(float f) {
    unsigned u = __float_as_uint(f);
    return (unsigned short)((u + 0x7FFFu + ((u >> 16) & 1u)) >> 16);
}

__global__ void qmean_kernel(const float* __restrict__ QF, float* __restrict__ out_q,
                             float* __restrict__ scale) {
    int b = blockIdx.x >> 1, c = blockIdx.x & 1;
    float s = 0.f;
    for (int m = threadIdx.x; m < MQn; m += blockDim.x)
        s += QF[(b * MQn + m) * 2 + c];
    __shared__ float sh[256];
    sh[threadIdx.x] = s;
    __syncthreads();
    for (int st = 128; st > 0; st >>= 1) {
        if (threadIdx.x < st) sh[threadIdx.x] += sh[threadIdx.x + st];
        __syncthreads();
    }
    if (threadIdx.x == 0) {
        float mean = sh[0] / (float)MQn;
        out_q[b * 2 + c] = mean;
        if (c == 0) scale[b] = mean;
    }
}

__global__ void mask_pool1_kernel(const float* __restrict__ xf, float* __restrict__ m1,
                                  float* __restrict__ c0) {
    int idx = blockIdx.x * blockDim.x + threadIdx.x;   // 0..65535
    int b = idx >> 15;
    int v = idx & 32767;
    int oz = v >> 10, oy = (v >> 5) & 31, ox = v & 31;
    float cnt = 0.f, mx = 0.f;
    for (int dz = 0; dz < 2; ++dz)
        for (int dy = 0; dy < 2; ++dy)
            for (int dx = 0; dx < 2; ++dx) {
                int z = 2 * oz + dz, y = 2 * oy + dy, x = 2 * ox + dx;
                size_t base = (size_t)b * 4 * D0 * D0 * D0 + ((size_t)z * D0 + y) * D0 + x;
                bool occ = false;
                for (int c = 0; c < 4; ++c)
                    occ = occ || (xf[base + (size_t)c * D0 * D0 * D0] != 0.f);
                if (occ) { cnt += 1.f; mx = 1.f; }
            }
    m1[idx] = mx;
    __shared__ float sh[256];
    sh[threadIdx.x] = cnt;
    __syncthreads();
    for (int st = 128; st > 0; st >>= 1) {
        if (threadIdx.x < st) sh[threadIdx.x] += sh[threadIdx.x + st];
        __syncthreads();
    }
    if (threadIdx.x == 0) atomicAdd(&c0[b], sh[0]);
}

__global__ void pool_kernel(const float* __restrict__ min_, float* __restrict__ mout,
                            float* __restrict__ cacc, int Din) {
    int Do = Din >> 1;
    int per = Do * Do * Do;
    int idx = blockIdx.x * blockDim.x + threadIdx.x;
    int b = idx / per;
    int v = idx % per;
    int oz = v / (Do * Do), oy = (v / Do) % Do, ox = v % Do;
    float s = 0.f, mx = 0.f;
    for (int dz = 0; dz < 2; ++dz)
        for (int dy = 0; dy < 2; ++dy)
            for (int dx = 0; dx < 2; ++dx) {
                float val = min_[(((size_t)b * Din + 2 * oz + dz) * Din + 2 * oy + dy) * Din + 2 * ox + dx];
                s += val;
                mx = fmaxf(mx, val);
            }
    mout[idx] = mx;
    __shared__ float sh[256];
    sh[threadIdx.x] = s;
    __syncthreads();
    for (int st = 128; st > 0; st >>= 1) {
        if (threadIdx.x < st) sh[threadIdx.x] += sh[threadIdx.x + st];
        __syncthreads();
    }
    if (threadIdx.x == 0) atomicAdd(&cacc[b], sh[0]);
}

__global__ void writek_kernel(const float* __restrict__ cnt, float* __restrict__ outk) {
    int i = threadIdx.x;
    if (i < 6) {
        int row = i >> 1, b = i & 1;
        float v = (row == 0) ? cnt[4 + b] : (row == 1 ? cnt[2 + b] : cnt[b]);
        outk[i] = v;
    }
}

// x_feat NCDHW fp32 -> CL bf16 [b][voxel][8] (4 real + 4 zero)
__global__ __launch_bounds__(256) void xcl_kernel(const float* __restrict__ xf,
                                                  unsigned short* __restrict__ xcl) {
    int idx = blockIdx.x * 256 + threadIdx.x;   // b*VOX + sp, VOX=262144
    if (idx >= 2 * 262144) return;
    int b = idx >> 18, sp = idx & 262143;
    bf16x8v o;
#pragma unroll
    for (int ci = 0; ci < 4; ++ci)
        o[ci] = (short)f2bf(xf[((size_t)b * 4 + ci) * 262144 + sp]);
#pragma unroll
    for (int ci = 4; ci < 8; ++ci) o[ci] = 0;
    *(bf16x8v*)&xcl[(size_t)idx * 8] = o;
}

// All 7 weight tensors -> bf16 [cs][nch][tap][n32][kc2][8], zero-guarded ci >= cinR.
constexpr int GS1 = 0,        GE1 = 64000;    // w1  cinP16 cinR4  nch1
constexpr int GS2 = 64000,    GE2 = 192000;   // g1  32 32 1
constexpr int GS3 = 192000,   GE3 = 448000;   // w2  32 32 2
constexpr int GS4 = 448000,   GE4 = 960000;   // g2  64 64 2
constexpr int GS5 = 960000,   GE5 = 1728000;  // w3  64 64 3
constexpr int GS6 = 1728000,  GE6 = 2880000;  // g3  96 96 3
constexpr int GS7 = 2880000,  GE7 = 4416000;  // w4  96 96 4
__global__ __launch_bounds__(256) void mwtrans_all_kernel(
        const float* __restrict__ w1, const float* __restrict__ g1,
        const float* __restrict__ w2, const float* __restrict__ g2,
        const float* __restrict__ w3, const float* __restrict__ g3,
        const float* __restrict__ w4, float* __restrict__ ws) {
    int idx = blockIdx.x * 256 + threadIdx.x;
    if (idx >= GE7) return;
    const float* src; unsigned short* dst; int nchn, cinR, o;
    if (idx < GE1)      { src = w1; dst = (unsigned short*)(ws + OFF_WC1); nchn = 1; cinR = 4;  o = idx - GS1; }
    else if (idx < GE2) { src = g1; dst = (unsigned short*)(ws + OFF_WG1); nchn = 1; cinR = 32; o = idx - GS2; }
    else if (idx < GE3) { src = w2; dst = (unsigned short*)(ws + OFF_WC2); nchn = 2; cinR = 32; o = idx - GS3; }
    else if (idx < GE4) { src = g2; dst = (unsigned short*)(ws + OFF_WG2); nchn = 2; cinR = 64; o = idx - GS4; }
    else if (idx < GE5) { src = w3; dst = (unsigned short*)(ws + OFF_WC3); nchn = 3; cinR = 64; o = idx - GS5; }
    else if (idx < GE6) { src = g3; dst = (unsigned short*)(ws + OFF_WG3); nchn = 3; cinR = 96; o = idx - GS6; }
    else                { src = w4; dst = (unsigned short*)(ws + OFF_WC4); nchn = 4; cinR = 96; o = idx - GS7; }
    int j  = o & 7;
    int kc = (o >> 3) & 1;
    int n  = (o >> 4) & 31;
    int q  = o >> 9;
    int tap = q % 125;
    int q2  = q / 125;
    int nch = q2 % nchn;
    int cs  = q2 / nchn;
    int co = nch * 32 + n;
    int ci = cs * 16 + kc * 8 + j;
    float v = (ci < cinR) ? src[((size_t)co * cinR + ci) * 125 + tap] : 0.f;
    dst[o] = f2bf(v);
}

// ===== stride-2 MFMA conv (conv1/2/3), parity-class LDS =====
// D[m=co][n=outvoxel] += W[m][k=ci] X[k][n] per tap. Tile: TZ z x 4 y x 8 x out.
// Input staged CL bf16 per parity class [pz][py][px][mz][my][mx] so every tap's
// wave read is a contiguous 4x8 half-grid patch (stride-1-like banking).
template<int DCIN, int COUTt, int DIN, int DOUT, int TZ, int CIG, bool EPI>
__global__ __launch_bounds__(256) void s2mconv_kernel(
    const unsigned short* __restrict__ in,   // CL bf16 [b][z][y][x][DCIN]
    const unsigned short* __restrict__ wb,   // [cs][nch][tap][n32][kc2][8]
    const float* __restrict__ bias,          // EPI only
    const float* __restrict__ mask,          // EPI only [b][VOX]
    const float* __restrict__ zerow,
    float* __restrict__ tout,                // CL fp32 [b][v][COUTt]
    unsigned short* __restrict__ sqout)      // EPI only: CL bf16 squares
{
    constexpr int NCH = COUTt / 32;
    constexpr int UPV = (DCIN == 8) ? 1 : 2;   // 16B units per voxel staged
    constexpr int LZR = 2 * TZ + 3;
    constexpr int MZW = (TZ == 4) ? 6 : 4;
    constexpr int MYW = 6, MXW = 10;
    constexpr int NU  = 8 * MZW * MYW * MXW * UPV;   // 2880 | 3840
    constexpr int NLOAD = (NU + 255) / 256;
    constexpr int NTZ = DOUT / TZ, NTY = DOUT / 4, NTX = DOUT / 8;
    constexpr int NT = NTZ * NTY * NTX * Bn;
    constexpr int VOX = DOUT * DOUT * DOUT;
    __shared__ unsigned short lds[NLOAD * 256 * 8];

    int bid = blockIdx.x;
    int tile = bid % NT;
    int cs = bid / NT;
    int r = tile;
    int tx0 = (r % NTX) * 8; r /= NTX;
    int ty0 = (r % NTY) * 4; r /= NTY;
    int tz0 = (r % NTZ) * TZ; int b = r / NTZ;

    int tid = threadIdx.x;
    int iz0 = 2 * tz0 - 2, iy0 = 2 * ty0 - 2, ix0 = 2 * tx0 - 2;
#pragma unroll
    for (int k = 0; k < NLOAD; ++k) {
        int u = tid + k * 256;
        int up = (UPV == 2) ? (u & 1) : 0;
        int v = (UPV == 2) ? (u >> 1) : u;
        int mx = v % MXW; int t = v / MXW;
        int my = t % MYW; t /= MYW;
        int mz = t % MZW; int cls = t / MZW;
        int px = cls & 1, py = (cls >> 1) & 1, pz = cls >> 2;
        int lz = 2 * mz + pz, ly = 2 * my + py, lx = 2 * mx + px;
        int gz = iz0 + lz, gy = iy0 + ly, gx = ix0 + lx;
        bool valid = (u < NU) && (cls < 8) && (lz < LZR) && (ly < 11) && (lx < 19) &&
                     (unsigned)gz < (unsigned)DIN && (unsigned)gy < (unsigned)DIN &&
                     (unsigned)gx < (unsigned)DIN;
        const unsigned short* g = valid
            ? in + ((((size_t)b * DIN + gz) * DIN + gy) * DIN + gx) * DCIN + cs * 16 + up * 8
            : (const unsigned short*)zerow;
        async_copy16((const float*)g, (float*)&lds[(size_t)(tid + k * 256) * 8]);
    }
    __syncthreads();

    int lane = tid & 63, w = tid >> 6;
    int zz, c0n, c1n;
    if (TZ == 4) { zz = w; c0n = 0; c1n = NCH; }
    else {
        zz = w & 1; int ch = w >> 1;
        constexpr int CH0 = (NCH + 1) / 2;
        c0n = ch * CH0; c1n = (c0n + CH0 < NCH) ? c0n + CH0 : NCH;
    }
    int n = lane & 31, kc = lane >> 5;
    int vy = n >> 3, vx = n & 7;

    f32x16v acc[NCH];
#pragma unroll
    for (int c = 0; c < NCH; ++c)
#pragma unroll
        for (int i = 0; i < 16; ++i) acc[c][i] = 0.f;

#pragma unroll 1
    for (int kz = 0; kz < 5; ++kz) {
        int mz = zz + (kz >> 1), pz = kz & 1;
#pragma unroll 1
        for (int ky = 0; ky < 5; ++ky) {
            int my = vy + (ky >> 1), py = ky & 1;
#pragma unroll
            for (int kx = 0; kx < 5; ++kx) {
                int px = kx & 1, mx = vx + (kx >> 1);
                int cls = pz * 4 + py * 2 + px;
                int unit = ((cls * MZW + mz) * MYW + my) * MXW + mx;
                int uoff = (UPV == 2) ? unit * 2 + kc : (kc ? NU : unit);
                bf16x8v dfrag = *(const bf16x8v*)&lds[(size_t)uoff * 8];
                int tap = (kz * 5 + ky) * 5 + kx;
                for (int c = c0n; c < c1n; ++c) {
                    const unsigned short* wp =
                        wb + (((size_t)(cs * NCH + c) * 125 + tap) << 9) + n * 16 + kc * 8;
                    bf16x8v wfrag = *(const bf16x8v*)wp;
                    acc[c] = __builtin_amdgcn_mfma_f32_32x32x16_bf16(wfrag, dfrag, acc[c], 0, 0, 0);
                }
            }
        }
    }

    int sp = ((tz0 + zz) * DOUT + (ty0 + vy)) * DOUT + (tx0 + vx);
    size_t base = ((size_t)b * VOX + sp) * COUTt;
    if (EPI) {
        float mval = mask[(size_t)b * VOX + sp];
        for (int c = c0n; c < c1n; ++c) {
#pragma unroll
            for (int g = 0; g < 4; ++g) {
                int cob = c * 32 + g * 8 + 4 * kc;
                v4f bi = *(const v4f*)&bias[cob];
                v4f vv; bf16x4v sv;
#pragma unroll
                for (int j = 0; j < 4; ++j) {
                    vv[j] = (acc[c][g * 4 + j] + bi[j]) * mval;
                    sv[j] = (short)f2bf(vv[j] * vv[j]);
                }
                *(v4f*)&tout[base + cob] = vv;
                *(bf16x4v*)&sqout[base + cob] = sv;
            }
        }
    } else {
        for (int c = c0n; c < c1n; ++c) {
#pragma unroll
            for (int rr = 0; rr < 16; ++rr) {
                int co = c * 32 + (rr & 3) + 8 * (rr >> 2) + 4 * kc;
                atomicAdd(&tout[base + co], acc[c][rr]);
            }
        }
    }
}

// ===== stride-1 MFMA conv (GDN denominators + conv4), R6-proven =====
template<int CINt, int COUTt, int Dd, int TZ, int YB, int CIG, int ZSPL, bool CLD>
__global__ __launch_bounds__(256) void mconv_kernel(
    const unsigned short* __restrict__ in,   // CL bf16 [b][z][y][x][CINt]
    const unsigned short* __restrict__ wb,
    const float* __restrict__ zerow,
    float* __restrict__ dout)                // CLD? CL fp32 : NCDHW fp32 (atomicAdd)
{
    constexpr int NCH = COUTt / 32;
    constexpr int LZ = TZ + 4, LYH = YB * 4 + 4, LXH = 12;
    constexpr int HV = LZ * LYH * LXH;
    constexpr int UN = 2 * HV;
    constexpr int NLOAD = (UN + 255) / 256;
    constexpr int NTZ = Dd / TZ, NTY = Dd / (YB * 4), NTX = Dd / 8;
    constexpr int NT = NTZ * NTY * NTX * Bn;
    constexpr int VOX = Dd * Dd * Dd;
    __shared__ unsigned short lds[NLOAD * 256 * 8];

    int bid = blockIdx.x;
    int tile = bid % NT; int rest = bid / NT;
    int cs = rest % CIG; int zig = rest / CIG;
    int r = tile;
    int tx0 = (r % NTX) * 8; r /= NTX;
    int ty0 = (r % NTY) * (YB * 4); r /= NTY;
    int tz0 = (r % NTZ) * TZ; int b = r / NTZ;

    int tid = threadIdx.x;
    int iz0 = tz0 - 2, iy0 = ty0 - 2, ix0 = tx0 - 2;
#pragma unroll
    for (int k = 0; k < NLOAD; ++k) {
        int u = tid + k * 256;
        int v = u >> 1, half = u & 1;
        int lx = v % LXH; int t = v / LXH;
        int ly = t % LYH, lz = t / LYH;
        int gz = iz0 + lz, gy = iy0 + ly, gx = ix0 + lx;
        bool valid = (v < HV) &&
                     (unsigned)gz < (unsigned)Dd && (unsigned)gy < (unsigned)Dd &&
                     (unsigned)gx < (unsigned)Dd;
        const unsigned short* g = valid
            ? in + ((((size_t)b * Dd + gz) * Dd + gy) * Dd + gx) * CINt + cs * 16 + half * 8
            : (const unsigned short*)zerow;
        async_copy16((const float*)g, (float*)&lds[(size_t)u * 8]);
    }
    __syncthreads();

    int lane = tid & 63, w = tid >> 6;
    int zz = (YB == 1) ? w : (w >> 1);
    int yb = (YB == 1) ? 0 : (w & 1);
    int n = lane & 31, kc = lane >> 5;
    int vy = yb * 4 + (n >> 3), vx = n & 7;

    f32x16v acc[NCH];
#pragma unroll
    for (int c = 0; c < NCH; ++c)
#pragma unroll
        for (int i = 0; i < 16; ++i) acc[c][i] = 0.f;

    int kzlo = (ZSPL == 5) ? zig : 0;
    int kzhi = (ZSPL == 5) ? zig + 1 : 5;
#pragma unroll 1
    for (int kz = kzlo; kz < kzhi; ++kz) {
#pragma unroll 1
        for (int ky = 0; ky < 5; ++ky) {
            int hvrow = ((zz + kz) * LYH + (vy + ky)) * LXH + vx;
#pragma unroll
            for (int kx = 0; kx < 5; ++kx) {
                bf16x8v dfrag = *(const bf16x8v*)&lds[(size_t)(hvrow + kx) * 16 + kc * 8];
                int tap = (kz * 5 + ky) * 5 + kx;
#pragma unroll
                for (int c = 0; c < NCH; ++c) {
                    const unsigned short* wp =
                        wb + (((size_t)(cs * NCH + c) * 125 + tap) << 9) + n * 16 + kc * 8;
                    bf16x8v wfrag = *(const bf16x8v*)wp;
                    acc[c] = __builtin_amdgcn_mfma_f32_32x32x16_bf16(wfrag, dfrag, acc[c], 0, 0, 0);
                }
            }
        }
    }

    int sp = ((tz0 + zz) * Dd + (ty0 + vy)) * Dd + (tx0 + vx);
#pragma unroll
    for (int c = 0; c < NCH; ++c) {
#pragma unroll
        for (int rr = 0; rr < 16; ++rr) {
            int co = c * 32 + (rr & 3) + 8 * (rr >> 2) + 4 * kc;
            if (CLD)
                atomicAdd(&dout[((size_t)b * VOX + sp) * COUTt + co], acc[c][rr]);
            else
                atomicAdd(&dout[(size_t)(b * COUTt + co) * VOX + sp], acc[c][rr]);
        }
    }
}

// CL epilogues
template<int C, int DOUT>
__global__ __launch_bounds__(256) void conv_epi_cl_kernel(float* __restrict__ buf,
        const float* __restrict__ bias, const float* __restrict__ mask,
        unsigned short* __restrict__ sq) {
    constexpr int VOX = DOUT * DOUT * DOUT;
    int idx = blockIdx.x * 256 + threadIdx.x;
    if (idx >= Bn * C * VOX) return;
    int co = idx % C;
    int sp = (idx / C) % VOX;
    int b = idx / (C * VOX);
    float v = (buf[idx] + bias[co]) * mask[(size_t)b * VOX + sp];
    buf[idx] = v;
    sq[idx] = f2bf(v * v);
}

template<int C, int DOUT>
__global__ __launch_bounds__(256) void gdn_epi_cl_kernel(const float* __restrict__ t,
        const float* __restrict__ den, const float* __restrict__ beta,
        const float* __restrict__ scale, unsigned short* __restrict__ ycl) {
    constexpr int VOX = DOUT * DOUT * DOUT;
    int idx = blockIdx.x * 256 + threadIdx.x;
    if (idx >= Bn * C * VOX) return;
    int co = idx % C;
    int b = idx / (C * VOX);
    float v = t[idx] * rsqrtf(beta[co] + den[idx]) * scale[b];
    ycl[idx] = f2bf(v);
}

// NCDHW final epilogue (conv4 -> out)
__global__ __launch_bounds__(256) void conv_epi4_kernel(float* __restrict__ buf,
        const float* __restrict__ bias, const float* __restrict__ mask) {
    constexpr int VOX = 512;
    int idx = blockIdx.x * 256 + threadIdx.x;
    if (idx >= Bn * 128 * VOX) return;
    int sp = idx % VOX;
    int co = (idx / VOX) % 128;
    int b = idx / (VOX * 128);
    buf[idx] = (buf[idx] + bias[co]) * mask[b * VOX + sp];
}

extern "C" void kernel_launch(void* const* d_in, const int* in_sizes, int n_in,
                              void* d_out, int out_size, void* d_ws, size_t ws_size,
                              hipStream_t stream) {
    const float* x_feat = (const float*)d_in[0];
    const float* QF     = (const float*)d_in[2];
    const float* w1 = (const float*)d_in[3];  const float* b1 = (const float*)d_in[4];
    const float* w2 = (const float*)d_in[5];  const float* b2 = (const float*)d_in[6];
    const float* w3 = (const float*)d_in[7];  const float* b3 = (const float*)d_in[8];
    const float* w4 = (const float*)d_in[9];  const float* b4 = (const float*)d_in[10];
    const float* beta1 = (const float*)d_in[11]; const float* gamma1 = (const float*)d_in[12];
    const float* beta2 = (const float*)d_in[13]; const float* gamma2 = (const float*)d_in[14];
    const float* beta3 = (const float*)d_in[15]; const float* gamma3 = (const float*)d_in[16];

    float* out = (float*)d_out;
    float* ws = (float*)d_ws;
    float* cnt   = ws + OFF_CNT;
    float* zerow = ws + OFF_ZERO;
    float* scale = ws + OFF_SCALE;
    float* m1 = ws + OFF_M1;  float* m2 = ws + OFF_M2;  float* m3 = ws + OFF_M3;
    float* t1 = ws + OFF_T1CL; float* t2 = ws + OFF_T2CL; float* t3 = ws + OFF_T3CL;
    float* d1 = ws + OFF_D1CL; float* d2 = ws + OFF_D2CL; float* d3 = ws + OFF_D3CL;
    unsigned short* xcl = (unsigned short*)(ws + OFF_XCL);
    unsigned short* y1c = (unsigned short*)(ws + OFF_Y1C);
    unsigned short* sq1 = (unsigned short*)(ws + OFF_SQ1);
    unsigned short* y2c = (unsigned short*)(ws + OFF_Y2C);
    unsigned short* sq2 = (unsigned short*)(ws + OFF_SQ2);
    unsigned short* y3c = (unsigned short*)(ws + OFF_Y3C);
    unsigned short* sq3 = (unsigned short*)(ws + OFF_SQ3);
    unsigned short* wc1 = (unsigned short*)(ws + OFF_WC1);
    unsigned short* wg1 = (unsigned short*)(ws + OFF_WG1);
    unsigned short* wc2 = (unsigned short*)(ws + OFF_WC2);
    unsigned short* wg2 = (unsigned short*)(ws + OFF_WG2);
    unsigned short* wc3 = (unsigned short*)(ws + OFF_WC3);
    unsigned short* wg3 = (unsigned short*)(ws + OFF_WG3);
    unsigned short* wc4 = (unsigned short*)(ws + OFF_WC4);

    hipMemsetAsync(ws, 0, ZERO_END * sizeof(float), stream);
    hipMemsetAsync(out + OUT_X, 0, 131072 * sizeof(float), stream);

    qmean_kernel<<<4, 256, 0, stream>>>(QF, out + OUT_Q, scale);
    mask_pool1_kernel<<<256, 256, 0, stream>>>(x_feat, m1, cnt + 0);
    pool_kernel<<<32, 256, 0, stream>>>(m1, m2, cnt + 2, D1);
    pool_kernel<<<4, 256, 0, stream>>>(m2, m3, cnt + 4, D2);
    writek_kernel<<<1, 64, 0, stream>>>(cnt, out + OUT_K);

    xcl_kernel<<<2048, 256, 0, stream>>>(x_feat, xcl);
    mwtrans_all_kernel<<<(GE7 + 255) / 256, 256, 0, stream>>>(
        w1, gamma1, w2, gamma2, w3, gamma3, w4, ws);

    // Stage 1: conv1 s2-MFMA (K-pad 16, inline epi -> t1 CL + sq1) ; GDN1 MFMA ; epi -> y1c
    s2mconv_kernel<8, 32, 64, 32, 4, 1, true>
        <<<512, 256, 0, stream>>>(xcl, wc1, b1, m1, zerow, t1, sq1);
    mconv_kernel<32, 32, 32, 4, 1, 2, 1, true>
        <<<1024, 256, 0, stream>>>(sq1, wg1, zerow, d1);
    gdn_epi_cl_kernel<32, 32><<<8192, 256, 0, stream>>>(t1, d1, beta1, scale, y1c);

    // Stage 2: conv2 s2-MFMA (cs x2 -> t2 CL atomics) ; epi(+sq2) ; GDN2 MFMA ; epi -> y2c
    s2mconv_kernel<32, 64, 32, 16, 2, 2, false>
        <<<256, 256, 0, stream>>>(y1c, wc2, nullptr, nullptr, zerow, t2, nullptr);
    conv_epi_cl_kernel<64, 16><<<2048, 256, 0, stream>>>(t2, b2, m2, sq2);
    mconv_kernel<64, 64, 16, 4, 1, 4, 1, true>
        <<<256, 256, 0, stream>>>(sq2, wg2, zerow, d2);
    gdn_epi_cl_kernel<64, 16><<<2048, 256, 0, stream>>>(t2, d2, beta2, scale, y2c);

    // Stage 3: conv3 s2-MFMA (cs x4 -> t3 CL atomics) ; epi(+sq3) ; GDN3 MFMA ; epi -> y3c
    s2mconv_kernel<64, 96, 16, 8, 2, 4, false>
        <<<64, 256, 0, stream>>>(y2c, wc3, nullptr, nullptr, zerow, t3, nullptr);
    conv_epi_cl_kernel<96, 8><<<384, 256, 0, stream>>>(t3, b3, m3, sq3);
    mconv_kernel<96, 96, 8, 2, 2, 6, 5, true>
        <<<240, 256, 0, stream>>>(sq3, wg3, zerow, d3);
    gdn_epi_cl_kernel<96, 8><<<384, 256, 0, stream>>>(t3, d3, beta3, scale, y3c);

    // Stage 4: conv4 s1-MFMA -> out NCDHW atomics ; final epilogue
    mconv_kernel<96, 128, 8, 2, 2, 6, 5, false>
        <<<240, 256, 0, stream>>>(y3c, wc4, zerow, out + OUT_X);
    conv_epi4_kernel<<<512, 256, 0, stream>>>(out + OUT_X, b4, m3);
}

// Round 9
// 702.018 us; speedup vs baseline: 2.6777x; 2.6777x over previous
//
#include <hip/hip_runtime.h>
#include <math.h>

// Problem constants
constexpr int Bn  = 2;
constexpr int MQn = 1024;
constexpr int D0 = 64, D1 = 32, D2 = 16, D3 = 8;

// Output layout (floats): x [2,128,8,8,8] = 131072, q [1,2,2] = 4, k [3,2] = 6
constexpr int OUT_X = 0;
constexpr int OUT_Q = 131072;
constexpr int OUT_K = 131076;

// Workspace layout (floats). Zero-initialized span first (single memset).
constexpr size_t OFF_CNT   = 0;
constexpr size_t OFF_ZERO  = 8;                    // 32B zero block for DMA padding
constexpr size_t OFF_T2CL  = 16;                   // CL fp32 2*16^3*64
constexpr size_t OFF_T3CL  = OFF_T2CL + 524288;    // CL fp32 2*8^3*96
constexpr size_t OFF_D1CL  = OFF_T3CL + 98304;     // CL fp32 2*32^3*32
constexpr size_t OFF_D2CL  = OFF_D1CL + 2097152;
constexpr size_t OFF_D3CL  = OFF_D2CL + 524288;
constexpr size_t ZERO_END  = OFF_D3CL + 98304;     // 3342352
// non-zeroed region
constexpr size_t OFF_SCALE = ZERO_END;             // 8
constexpr size_t OFF_M1    = OFF_SCALE + 8;        // 2*32^3
constexpr size_t OFF_M2    = OFF_M1 + 65536;
constexpr size_t OFF_M3    = OFF_M2 + 8192;
constexpr size_t OFF_T1CL  = OFF_M3 + 1024;        // CL fp32 2*32^3*32
constexpr size_t OFF_XCL   = OFF_T1CL + 2097152;   // CL bf16 2*64^3*8 sh
constexpr size_t OFF_Y1C   = OFF_XCL + 2097152;    // CL bf16 2*32^3*32 sh
constexpr size_t OFF_SQ1   = OFF_Y1C + 1048576;    // CL bf16
constexpr size_t OFF_Y2C   = OFF_SQ1 + 1048576;    // CL bf16 2*16^3*64 sh
constexpr size_t OFF_SQ2   = OFF_Y2C + 262144;
constexpr size_t OFF_Y3C   = OFF_SQ2 + 262144;     // CL bf16 2*8^3*96 sh
constexpr size_t OFF_SQ3   = OFF_Y3C + 49152;
// bf16 MFMA weights [cs][nch][tap][n32][kc2][8]
constexpr size_t OFF_WC1   = OFF_SQ3 + 49152;      // 64000 sh
constexpr size_t OFF_WG1   = OFF_WC1 + 32000;      // 128000 sh
constexpr size_t OFF_WC2   = OFF_WG1 + 64000;      // 256000 sh
constexpr size_t OFF_WG2   = OFF_WC2 + 128000;     // 512000 sh
constexpr size_t OFF_WC3   = OFF_WG2 + 256000;     // 768000 sh
constexpr size_t OFF_WG3   = OFF_WC3 + 384000;     // 1152000 sh
constexpr size_t OFF_WC4   = OFF_WG3 + 576000;     // 1536000 sh
// end ~12.5M floats (~50 MB)

typedef float v4f __attribute__((ext_vector_type(4)));
typedef __attribute__((ext_vector_type(4)))  short bf16x4v;
typedef __attribute__((ext_vector_type(8)))  short bf16x8v;
typedef __attribute__((ext_vector_type(16))) float f32x16v;

__device__ __forceinline__ void async_copy16(const float* g, float* l) {
    __builtin_amdgcn_global_load_lds(
        (const __attribute__((address_space(1))) void*)g,
        (__attribute__((address_space(3))) void*)l, 16, 0, 0);
}
__device__ __forceinline__ unsigned short f2bf(float f) {
    unsigned u = __float_as_uint(f);
    return (unsigned short)((u + 0x7FFFu + ((u >> 16) & 1u)) >> 16);
}

__global__ void qmean_kernel(const float* __restrict__ QF, float* __restrict__ out_q,
                             float* __restrict__ scale) {
    int b = blockIdx.x >> 1, c = blockIdx.x & 1;
    float s = 0.f;
    for (int m = threadIdx.x; m < MQn; m += blockDim.x)
        s += QF[(b * MQn + m) * 2 + c];
    __shared__ float sh[256];
    sh[threadIdx.x] = s;
    __syncthreads();
    for (int st = 128; st > 0; st >>= 1) {
        if (threadIdx.x < st) sh[threadIdx.x] += sh[threadIdx.x + st];
        __syncthreads();
    }
    if (threadIdx.x == 0) {
        float mean = sh[0] / (float)MQn;
        out_q[b * 2 + c] = mean;
        if (c == 0) scale[b] = mean;
    }
}

__global__ void mask_pool1_kernel(const float* __restrict__ xf, float* __restrict__ m1,
                                  float* __restrict__ c0) {
    int idx = blockIdx.x * blockDim.x + threadIdx.x;   // 0..65535
    int b = idx >> 15;
    int v = idx & 32767;
    int oz = v >> 10, oy = (v >> 5) & 31, ox = v & 31;
    float cnt = 0.f, mx = 0.f;
    for (int dz = 0; dz < 2; ++dz)
        for (int dy = 0; dy < 2; ++dy)
            for (int dx = 0; dx < 2; ++dx) {
                int z = 2 * oz + dz, y = 2 * oy + dy, x = 2 * ox + dx;
                size_t base = (size_t)b * 4 * D0 * D0 * D0 + ((size_t)z * D0 + y) * D0 + x;
                bool occ = false;
                for (int c = 0; c < 4; ++c)
                    occ = occ || (xf[base + (size_t)c * D0 * D0 * D0] != 0.f);
                if (occ) { cnt += 1.f; mx = 1.f; }
            }
    m1[idx] = mx;
    __shared__ float sh[256];
    sh[threadIdx.x] = cnt;
    __syncthreads();
    for (int st = 128; st > 0; st >>= 1) {
        if (threadIdx.x < st) sh[threadIdx.x] += sh[threadIdx.x + st];
        __syncthreads();
    }
    if (threadIdx.x == 0) atomicAdd(&c0[b], sh[0]);
}

__global__ void pool_kernel(const float* __restrict__ min_, float* __restrict__ mout,
                            float* __restrict__ cacc, int Din) {
    int Do = Din >> 1;
    int per = Do * Do * Do;
    int idx = blockIdx.x * blockDim.x + threadIdx.x;
    int b = idx / per;
    int v = idx % per;
    int oz = v / (Do * Do), oy = (v / Do) % Do, ox = v % Do;
    float s = 0.f, mx = 0.f;
    for (int dz = 0; dz < 2; ++dz)
        for (int dy = 0; dy < 2; ++dy)
            for (int dx = 0; dx < 2; ++dx) {
                float val = min_[(((size_t)b * Din + 2 * oz + dz) * Din + 2 * oy + dy) * Din + 2 * ox + dx];
                s += val;
                mx = fmaxf(mx, val);
            }
    mout[idx] = mx;
    __shared__ float sh[256];
    sh[threadIdx.x] = s;
    __syncthreads();
    for (int st = 128; st > 0; st >>= 1) {
        if (threadIdx.x < st) sh[threadIdx.x] += sh[threadIdx.x + st];
        __syncthreads();
    }
    if (threadIdx.x == 0) atomicAdd(&cacc[b], sh[0]);
}

__global__ void writek_kernel(const float* __restrict__ cnt, float* __restrict__ outk) {
    int i = threadIdx.x;
    if (i < 6) {
        int row = i >> 1, b = i & 1;
        float v = (row == 0) ? cnt[4 + b] : (row == 1 ? cnt[2 + b] : cnt[b]);
        outk[i] = v;
    }
}

// x_feat NCDHW fp32 -> CL bf16 [b][voxel][8] (4 real + 4 zero)
__global__ __launch_bounds__(256) void xcl_kernel(const float* __restrict__ xf,
                                                  unsigned short* __restrict__ xcl) {
    int idx = blockIdx.x * 256 + threadIdx.x;   // b*VOX + sp, VOX=262144
    if (idx >= 2 * 262144) return;
    int b = idx >> 18, sp = idx & 262143;
    bf16x8v o;
#pragma unroll
    for (int ci = 0; ci < 4; ++ci)
        o[ci] = (short)f2bf(xf[((size_t)b * 4 + ci) * 262144 + sp]);
#pragma unroll
    for (int ci = 4; ci < 8; ++ci) o[ci] = 0;
    *(bf16x8v*)&xcl[(size_t)idx * 8] = o;
}

// All 7 weight tensors -> bf16 [cs][nch][tap][n32][kc2][8], zero-guarded ci >= cinR.
constexpr int GS1 = 0,        GE1 = 64000;    // w1  cinP16 cinR4  nch1
constexpr int GS2 = 64000,    GE2 = 192000;   // g1  32 32 1
constexpr int GS3 = 192000,   GE3 = 448000;   // w2  32 32 2
constexpr int GS4 = 448000,   GE4 = 960000;   // g2  64 64 2
constexpr int GS5 = 960000,   GE5 = 1728000;  // w3  64 64 3
constexpr int GS6 = 1728000,  GE6 = 2880000;  // g3  96 96 3
constexpr int GS7 = 2880000,  GE7 = 4416000;  // w4  96 96 4
__global__ __launch_bounds__(256) void mwtrans_all_kernel(
        const float* __restrict__ w1, const float* __restrict__ g1,
        const float* __restrict__ w2, const float* __restrict__ g2,
        const float* __restrict__ w3, const float* __restrict__ g3,
        const float* __restrict__ w4, float* __restrict__ ws) {
    int idx = blockIdx.x * 256 + threadIdx.x;
    if (idx >= GE7) return;
    const float* src; unsigned short* dst; int nchn, cinR, o;
    if (idx < GE1)      { src = w1; dst = (unsigned short*)(ws + OFF_WC1); nchn = 1; cinR = 4;  o = idx - GS1; }
    else if (idx < GE2) { src = g1; dst = (unsigned short*)(ws + OFF_WG1); nchn = 1; cinR = 32; o = idx - GS2; }
    else if (idx < GE3) { src = w2; dst = (unsigned short*)(ws + OFF_WC2); nchn = 2; cinR = 32; o = idx - GS3; }
    else if (idx < GE4) { src = g2; dst = (unsigned short*)(ws + OFF_WG2); nchn = 2; cinR = 64; o = idx - GS4; }
    else if (idx < GE5) { src = w3; dst = (unsigned short*)(ws + OFF_WC3); nchn = 3; cinR = 64; o = idx - GS5; }
    else if (idx < GE6) { src = g3; dst = (unsigned short*)(ws + OFF_WG3); nchn = 3; cinR = 96; o = idx - GS6; }
    else                { src = w4; dst = (unsigned short*)(ws + OFF_WC4); nchn = 4; cinR = 96; o = idx - GS7; }
    int j  = o & 7;
    int kc = (o >> 3) & 1;
    int n  = (o >> 4) & 31;
    int q  = o >> 9;
    int tap = q % 125;
    int q2  = q / 125;
    int nch = q2 % nchn;
    int cs  = q2 / nchn;
    int co = nch * 32 + n;
    int ci = cs * 16 + kc * 8 + j;
    float v = (ci < cinR) ? src[((size_t)co * cinR + ci) * 125 + tap] : 0.f;
    dst[o] = f2bf(v);
}

// ===== stride-2 MFMA conv (conv1/2/3), parity-class LDS =====
// Waves: NZW = TZ z-slices x NCW = 4/TZ channel groups of constexpr WCH chunks.
// acc indexed ONLY by unrolled cc (compile-time) -> stays in registers.
template<int DCIN, int COUTt, int DIN, int DOUT, int TZ, int CIG, bool EPI>
__global__ __launch_bounds__(256) void s2mconv_kernel(
    const unsigned short* __restrict__ in,   // CL bf16 [b][z][y][x][DCIN]
    const unsigned short* __restrict__ wb,   // [cs][nch][tap][n32][kc2][8]
    const float* __restrict__ bias,          // EPI only
    const float* __restrict__ mask,          // EPI only [b][VOX]
    const float* __restrict__ zerow,
    float* __restrict__ tout,                // CL fp32 [b][v][COUTt]
    unsigned short* __restrict__ sqout)      // EPI only: CL bf16 squares
{
    constexpr int NCH = COUTt / 32;
    constexpr int NZW = TZ;                  // z-slices == waves in z (TZ in {2,4})
    constexpr int NCW = 4 / NZW;             // channel groups
    constexpr int WCH = (NCH + NCW - 1) / NCW;
    constexpr int UPV = (DCIN == 8) ? 1 : 2; // 16B units per voxel staged
    constexpr int LZR = 2 * TZ + 3;
    constexpr int MZW = (TZ == 4) ? 6 : 4;
    constexpr int MYW = 6, MXW = 10;
    constexpr int NU  = 8 * MZW * MYW * MXW * UPV;
    constexpr int NLOAD = (NU + 255) / 256;
    constexpr int NTZ = DOUT / TZ, NTY = DOUT / 4, NTX = DOUT / 8;
    constexpr int NT = NTZ * NTY * NTX * Bn;
    constexpr int VOX = DOUT * DOUT * DOUT;
    __shared__ unsigned short lds[NLOAD * 256 * 8];

    int bid = blockIdx.x;
    int tile = bid % NT;
    int cs = bid / NT;
    int r = tile;
    int tx0 = (r % NTX) * 8; r /= NTX;
    int ty0 = (r % NTY) * 4; r /= NTY;
    int tz0 = (r % NTZ) * TZ; int b = r / NTZ;

    int tid = threadIdx.x;
    int iz0 = 2 * tz0 - 2, iy0 = 2 * ty0 - 2, ix0 = 2 * tx0 - 2;
#pragma unroll
    for (int k = 0; k < NLOAD; ++k) {
        int u = tid + k * 256;
        int up = (UPV == 2) ? (u & 1) : 0;
        int v = (UPV == 2) ? (u >> 1) : u;
        int mx = v % MXW; int t = v / MXW;
        int my = t % MYW; t /= MYW;
        int mz = t % MZW; int cls = t / MZW;
        int px = cls & 1, py = (cls >> 1) & 1, pz = cls >> 2;
        int lz = 2 * mz + pz, ly = 2 * my + py, lx = 2 * mx + px;
        int gz = iz0 + lz, gy = iy0 + ly, gx = ix0 + lx;
        bool valid = (u < NU) && (cls < 8) && (lz < LZR) && (ly < 11) && (lx < 19) &&
                     (unsigned)gz < (unsigned)DIN && (unsigned)gy < (unsigned)DIN &&
                     (unsigned)gx < (unsigned)DIN;
        const unsigned short* g = valid
            ? in + ((((size_t)b * DIN + gz) * DIN + gy) * DIN + gx) * DCIN + cs * 16 + up * 8
            : (const unsigned short*)zerow;
        async_copy16((const float*)g, (float*)&lds[(size_t)(tid + k * 256) * 8]);
    }
    __syncthreads();

    int lane = tid & 63, w = tid >> 6;
    int zz = w % NZW;
    int ch = w / NZW;            // 0..NCW-1 (wave-uniform)
    int n = lane & 31, kc = lane >> 5;
    int vy = n >> 3, vx = n & 7;

    f32x16v acc[WCH];
#pragma unroll
    for (int cc = 0; cc < WCH; ++cc)
#pragma unroll
        for (int i = 0; i < 16; ++i) acc[cc][i] = 0.f;

#pragma unroll 1
    for (int kz = 0; kz < 5; ++kz) {
        int mz = zz + (kz >> 1), pz = kz & 1;
#pragma unroll 1
        for (int ky = 0; ky < 5; ++ky) {
            int my = vy + (ky >> 1), py = ky & 1;
#pragma unroll
            for (int kx = 0; kx < 5; ++kx) {
                int px = kx & 1, mx = vx + (kx >> 1);
                int cls = pz * 4 + py * 2 + px;
                int unit = ((cls * MZW + mz) * MYW + my) * MXW + mx;
                int uoff = (UPV == 2) ? unit * 2 + kc : (kc ? NU : unit);
                bf16x8v dfrag = *(const bf16x8v*)&lds[(size_t)uoff * 8];
                int tap = (kz * 5 + ky) * 5 + kx;
#pragma unroll
                for (int cc = 0; cc < WCH; ++cc) {
                    int c = ch * WCH + cc;
                    if (c < NCH) {
                        const unsigned short* wp =
                            wb + (((size_t)(cs * NCH + c) * 125 + tap) << 9) + n * 16 + kc * 8;
                        bf16x8v wfrag = *(const bf16x8v*)wp;
                        acc[cc] = __builtin_amdgcn_mfma_f32_32x32x16_bf16(wfrag, dfrag, acc[cc], 0, 0, 0);
                    }
                }
            }
        }
    }

    int sp = ((tz0 + zz) * DOUT + (ty0 + vy)) * DOUT + (tx0 + vx);
    size_t base = ((size_t)b * VOX + sp) * COUTt;
    if (EPI) {
        float mval = mask[(size_t)b * VOX + sp];
#pragma unroll
        for (int cc = 0; cc < WCH; ++cc) {
            int c = ch * WCH + cc;
            if (c < NCH) {
#pragma unroll
                for (int g = 0; g < 4; ++g) {
                    int cob = c * 32 + g * 8 + 4 * kc;
                    v4f bi = *(const v4f*)&bias[cob];
                    v4f vv; bf16x4v sv;
#pragma unroll
                    for (int j = 0; j < 4; ++j) {
                        vv[j] = (acc[cc][g * 4 + j] + bi[j]) * mval;
                        sv[j] = (short)f2bf(vv[j] * vv[j]);
                    }
                    *(v4f*)&tout[base + cob] = vv;
                    *(bf16x4v*)&sqout[base + cob] = sv;
                }
            }
        }
    } else {
#pragma unroll
        for (int cc = 0; cc < WCH; ++cc) {
            int c = ch * WCH + cc;
            if (c < NCH) {
#pragma unroll
                for (int rr = 0; rr < 16; ++rr) {
                    int co = c * 32 + (rr & 3) + 8 * (rr >> 2) + 4 * kc;
                    atomicAdd(&tout[base + co], acc[cc][rr]);
                }
            }
        }
    }
}

// ===== stride-1 MFMA conv (GDN denominators + conv4), R6-proven =====
template<int CINt, int COUTt, int Dd, int TZ, int YB, int CIG, int ZSPL, bool CLD>
__global__ __launch_bounds__(256) void mconv_kernel(
    const unsigned short* __restrict__ in,   // CL bf16 [b][z][y][x][CINt]
    const unsigned short* __restrict__ wb,
    const float* __restrict__ zerow,
    float* __restrict__ dout)                // CLD? CL fp32 : NCDHW fp32 (atomicAdd)
{
    constexpr int NCH = COUTt / 32;
    constexpr int LZ = TZ + 4, LYH = YB * 4 + 4, LXH = 12;
    constexpr int HV = LZ * LYH * LXH;
    constexpr int UN = 2 * HV;
    constexpr int NLOAD = (UN + 255) / 256;
    constexpr int NTZ = Dd / TZ, NTY = Dd / (YB * 4), NTX = Dd / 8;
    constexpr int NT = NTZ * NTY * NTX * Bn;
    constexpr int VOX = Dd * Dd * Dd;
    __shared__ unsigned short lds[NLOAD * 256 * 8];

    int bid = blockIdx.x;
    int tile = bid % NT; int rest = bid / NT;
    int cs = rest % CIG; int zig = rest / CIG;
    int r = tile;
    int tx0 = (r % NTX) * 8; r /= NTX;
    int ty0 = (r % NTY) * (YB * 4); r /= NTY;
    int tz0 = (r % NTZ) * TZ; int b = r / NTZ;

    int tid = threadIdx.x;
    int iz0 = tz0 - 2, iy0 = ty0 - 2, ix0 = tx0 - 2;
#pragma unroll
    for (int k = 0; k < NLOAD; ++k) {
        int u = tid + k * 256;
        int v = u >> 1, half = u & 1;
        int lx = v % LXH; int t = v / LXH;
        int ly = t % LYH, lz = t / LYH;
        int gz = iz0 + lz, gy = iy0 + ly, gx = ix0 + lx;
        bool valid = (v < HV) &&
                     (unsigned)gz < (unsigned)Dd && (unsigned)gy < (unsigned)Dd &&
                     (unsigned)gx < (unsigned)Dd;
        const unsigned short* g = valid
            ? in + ((((size_t)b * Dd + gz) * Dd + gy) * Dd + gx) * CINt + cs * 16 + half * 8
            : (const unsigned short*)zerow;
        async_copy16((const float*)g, (float*)&lds[(size_t)u * 8]);
    }
    __syncthreads();

    int lane = tid & 63, w = tid >> 6;
    int zz = (YB == 1) ? w : (w >> 1);
    int yb = (YB == 1) ? 0 : (w & 1);
    int n = lane & 31, kc = lane >> 5;
    int vy = yb * 4 + (n >> 3), vx = n & 7;

    f32x16v acc[NCH];
#pragma unroll
    for (int c = 0; c < NCH; ++c)
#pragma unroll
        for (int i = 0; i < 16; ++i) acc[c][i] = 0.f;

    int kzlo = (ZSPL == 5) ? zig : 0;
    int kzhi = (ZSPL == 5) ? zig + 1 : 5;
#pragma unroll 1
    for (int kz = kzlo; kz < kzhi; ++kz) {
#pragma unroll 1
        for (int ky = 0; ky < 5; ++ky) {
            int hvrow = ((zz + kz) * LYH + (vy + ky)) * LXH + vx;
#pragma unroll
            for (int kx = 0; kx < 5; ++kx) {
                bf16x8v dfrag = *(const bf16x8v*)&lds[(size_t)(hvrow + kx) * 16 + kc * 8];
                int tap = (kz * 5 + ky) * 5 + kx;
#pragma unroll
                for (int c = 0; c < NCH; ++c) {
                    const unsigned short* wp =
                        wb + (((size_t)(cs * NCH + c) * 125 + tap) << 9) + n * 16 + kc * 8;
                    bf16x8v wfrag = *(const bf16x8v*)wp;
                    acc[c] = __builtin_amdgcn_mfma_f32_32x32x16_bf16(wfrag, dfrag, acc[c], 0, 0, 0);
                }
            }
        }
    }

    int sp = ((tz0 + zz) * Dd + (ty0 + vy)) * Dd + (tx0 + vx);
#pragma unroll
    for (int c = 0; c < NCH; ++c) {
#pragma unroll
        for (int rr = 0; rr < 16; ++rr) {
            int co = c * 32 + (rr & 3) + 8 * (rr >> 2) + 4 * kc;
            if (CLD)
                atomicAdd(&dout[((size_t)b * VOX + sp) * COUTt + co], acc[c][rr]);
            else
                atomicAdd(&dout[(size_t)(b * COUTt + co) * VOX + sp], acc[c][rr]);
        }
    }
}

// CL epilogues
template<int C, int DOUT>
__global__ __launch_bounds__(256) void conv_epi_cl_kernel(float* __restrict__ buf,
        const float* __restrict__ bias, const float* __restrict__ mask,
        unsigned short* __restrict__ sq) {
    constexpr int VOX = DOUT * DOUT * DOUT;
    int idx = blockIdx.x * 256 + threadIdx.x;
    if (idx >= Bn * C * VOX) return;
    int co = idx % C;
    int sp = (idx / C) % VOX;
    int b = idx / (C * VOX);
    float v = (buf[idx] + bias[co]) * mask[(size_t)b * VOX + sp];
    buf[idx] = v;
    sq[idx] = f2bf(v * v);
}

template<int C, int DOUT>
__global__ __launch_bounds__(256) void gdn_epi_cl_kernel(const float* __restrict__ t,
        const float* __restrict__ den, const float* __restrict__ beta,
        const float* __restrict__ scale, unsigned short* __restrict__ ycl) {
    constexpr int VOX = DOUT * DOUT * DOUT;
    int idx = blockIdx.x * 256 + threadIdx.x;
    if (idx >= Bn * C * VOX) return;
    int co = idx % C;
    int b = idx / (C * VOX);
    float v = t[idx] * rsqrtf(beta[co] + den[idx]) * scale[b];
    ycl[idx] = f2bf(v);
}

// NCDHW final epilogue (conv4 -> out)
__global__ __launch_bounds__(256) void conv_epi4_kernel(float* __restrict__ buf,
        const float* __restrict__ bias, const float* __restrict__ mask) {
    constexpr int VOX = 512;
    int idx = blockIdx.x * 256 + threadIdx.x;
    if (idx >= Bn * 128 * VOX) return;
    int sp = idx % VOX;
    int co = (idx / VOX) % 128;
    int b = idx / (VOX * 128);
    buf[idx] = (buf[idx] + bias[co]) * mask[b * VOX + sp];
}

extern "C" void kernel_launch(void* const* d_in, const int* in_sizes, int n_in,
                              void* d_out, int out_size, void* d_ws, size_t ws_size,
                              hipStream_t stream) {
    const float* x_feat = (const float*)d_in[0];
    const float* QF     = (const float*)d_in[2];
    const float* w1 = (const float*)d_in[3];  const float* b1 = (const float*)d_in[4];
    const float* w2 = (const float*)d_in[5];  const float* b2 = (const float*)d_in[6];
    const float* w3 = (const float*)d_in[7];  const float* b3 = (const float*)d_in[8];
    const float* w4 = (const float*)d_in[9];  const float* b4 = (const float*)d_in[10];
    const float* beta1 = (const float*)d_in[11]; const float* gamma1 = (const float*)d_in[12];
    const float* beta2 = (const float*)d_in[13]; const float* gamma2 = (const float*)d_in[14];
    const float* beta3 = (const float*)d_in[15]; const float* gamma3 = (const float*)d_in[16];

    float* out = (float*)d_out;
    float* ws = (float*)d_ws;
    float* cnt   = ws + OFF_CNT;
    float* zerow = ws + OFF_ZERO;
    float* scale = ws + OFF_SCALE;
    float* m1 = ws + OFF_M1;  float* m2 = ws + OFF_M2;  float* m3 = ws + OFF_M3;
    float* t1 = ws + OFF_T1CL; float* t2 = ws + OFF_T2CL; float* t3 = ws + OFF_T3CL;
    float* d1 = ws + OFF_D1CL; float* d2 = ws + OFF_D2CL; float* d3 = ws + OFF_D3CL;
    unsigned short* xcl = (unsigned short*)(ws + OFF_XCL);
    unsigned short* y1c = (unsigned short*)(ws + OFF_Y1C);
    unsigned short* sq1 = (unsigned short*)(ws + OFF_SQ1);
    unsigned short* y2c = (unsigned short*)(ws + OFF_Y2C);
    unsigned short* sq2 = (unsigned short*)(ws + OFF_SQ2);
    unsigned short* y3c = (unsigned short*)(ws + OFF_Y3C);
    unsigned short* sq3 = (unsigned short*)(ws + OFF_SQ3);
    unsigned short* wc1 = (unsigned short*)(ws + OFF_WC1);
    unsigned short* wg1 = (unsigned short*)(ws + OFF_WG1);
    unsigned short* wc2 = (unsigned short*)(ws + OFF_WC2);
    unsigned short* wg2 = (unsigned short*)(ws + OFF_WG2);
    unsigned short* wc3 = (unsigned short*)(ws + OFF_WC3);
    unsigned short* wg3 = (unsigned short*)(ws + OFF_WG3);
    unsigned short* wc4 = (unsigned short*)(ws + OFF_WC4);

    hipMemsetAsync(ws, 0, ZERO_END * sizeof(float), stream);
    hipMemsetAsync(out + OUT_X, 0, 131072 * sizeof(float), stream);

    qmean_kernel<<<4, 256, 0, stream>>>(QF, out + OUT_Q, scale);
    mask_pool1_kernel<<<256, 256, 0, stream>>>(x_feat, m1, cnt + 0);
    pool_kernel<<<32, 256, 0, stream>>>(m1, m2, cnt + 2, D1);
    pool_kernel<<<4, 256, 0, stream>>>(m2, m3, cnt + 4, D2);
    writek_kernel<<<1, 64, 0, stream>>>(cnt, out + OUT_K);

    xcl_kernel<<<2048, 256, 0, stream>>>(x_feat, xcl);
    mwtrans_all_kernel<<<(GE7 + 255) / 256, 256, 0, stream>>>(
        w1, gamma1, w2, gamma2, w3, gamma3, w4, ws);

    // Stage 1: conv1 s2-MFMA (K-pad 16, inline epi -> t1 CL + sq1) ; GDN1 MFMA ; epi -> y1c
    s2mconv_kernel<8, 32, 64, 32, 4, 1, true>
        <<<512, 256, 0, stream>>>(xcl, wc1, b1, m1, zerow, t1, sq1);
    mconv_kernel<32, 32, 32, 4, 1, 2, 1, true>
        <<<1024, 256, 0, stream>>>(sq1, wg1, zerow, d1);
    gdn_epi_cl_kernel<32, 32><<<8192, 256, 0, stream>>>(t1, d1, beta1, scale, y1c);

    // Stage 2: conv2 s2-MFMA (cs x2 -> t2 CL atomics) ; epi(+sq2) ; GDN2 MFMA ; epi -> y2c
    s2mconv_kernel<32, 64, 32, 16, 2, 2, false>
        <<<256, 256, 0, stream>>>(y1c, wc2, nullptr, nullptr, zerow, t2, nullptr);
    conv_epi_cl_kernel<64, 16><<<2048, 256, 0, stream>>>(t2, b2, m2, sq2);
    mconv_kernel<64, 64, 16, 4, 1, 4, 1, true>
        <<<256, 256, 0, stream>>>(sq2, wg2, zerow, d2);
    gdn_epi_cl_kernel<64, 16><<<2048, 256, 0, stream>>>(t2, d2, beta2, scale, y2c);

    // Stage 3: conv3 s2-MFMA (cs x4 -> t3 CL atomics) ; epi(+sq3) ; GDN3 MFMA ; epi -> y3c
    s2mconv_kernel<64, 96, 16, 8, 2, 4, false>
        <<<64, 256, 0, stream>>>(y2c, wc3, nullptr, nullptr, zerow, t3, nullptr);
    conv_epi_cl_kernel<96, 8><<<384, 256, 0, stream>>>(t3, b3, m3, sq3);
    mconv_kernel<96, 96, 8, 2, 2, 6, 5, true>
        <<<240, 256, 0, stream>>>(sq3, wg3, zerow, d3);
    gdn_epi_cl_kernel<96, 8><<<384, 256, 0, stream>>>(t3, d3, beta3, scale, y3c);

    // Stage 4: conv4 s1-MFMA -> out NCDHW atomics ; final epilogue
    mconv_kernel<96, 128, 8, 2, 2, 6, 5, false>
        <<<240, 256, 0, stream>>>(y3c, wc4, zerow, out + OUT_X);
    conv_epi4_kernel<<<512, 256, 0, stream>>>(out + OUT_X, b4, m3);
}

// Round 10
// 592.025 us; speedup vs baseline: 3.1752x; 1.1858x over previous
//
#include <hip/hip_runtime.h>
#include <math.h>

// Problem constants
constexpr int Bn  = 2;
constexpr int MQn = 1024;
constexpr int D0 = 64, D1 = 32, D2 = 16, D3 = 8;

// Output layout (floats): x [2,128,8,8,8] = 131072, q [1,2,2] = 4, k [3,2] = 6
constexpr int OUT_X = 0;
constexpr int OUT_Q = 131072;
constexpr int OUT_K = 131076;

// Workspace layout (floats). Zero-initialized span first (single memset).
constexpr size_t OFF_CNT   = 0;
constexpr size_t OFF_ZERO  = 8;                    // 32B zero block for DMA padding
constexpr size_t OFF_T3CL  = 16;                   // CL fp32 2*8^3*96 (conv3 atomics)
constexpr size_t OFF_D3CL  = OFF_T3CL + 98304;     // CL fp32 (gdn3 atomics)
constexpr size_t ZERO_END  = OFF_D3CL + 98304;     // 196624
// non-zeroed region
constexpr size_t OFF_SCALE = 196624;
constexpr size_t OFF_M1    = 196632;               // 2*32^3
constexpr size_t OFF_M2    = OFF_M1 + 65536;
constexpr size_t OFF_M3    = OFF_M2 + 8192;
constexpr size_t OFF_T1CL  = OFF_M3 + 1024;        // CL fp32 2*32^3*32
constexpr size_t OFF_T2CL  = OFF_T1CL + 2097152;   // CL fp32 2*16^3*64
constexpr size_t OFF_XCL   = OFF_T2CL + 524288;    // CL bf16 2*64^3*8 sh
constexpr size_t OFF_Y1C   = OFF_XCL + 2097152;    // CL bf16 2*32^3*32 sh
constexpr size_t OFF_SQ1   = OFF_Y1C + 1048576;
constexpr size_t OFF_Y2C   = OFF_SQ1 + 1048576;    // CL bf16 2*16^3*64 sh
constexpr size_t OFF_SQ2   = OFF_Y2C + 262144;
constexpr size_t OFF_Y3C   = OFF_SQ2 + 262144;     // CL bf16 2*8^3*96 sh
constexpr size_t OFF_SQ3   = OFF_Y3C + 49152;
// bf16 MFMA weights [cs][nch][tap][n32][kc2][8]
constexpr size_t OFF_WC1   = OFF_SQ3 + 49152;      // 64000 sh
constexpr size_t OFF_WG1   = OFF_WC1 + 32000;      // 128000 sh
constexpr size_t OFF_WC2   = OFF_WG1 + 64000;      // 256000 sh
constexpr size_t OFF_WG2   = OFF_WC2 + 128000;     // 512000 sh
constexpr size_t OFF_WC3   = OFF_WG2 + 256000;     // 768000 sh
constexpr size_t OFF_WG3   = OFF_WC3 + 384000;     // 1152000 sh
constexpr size_t OFF_WC4   = OFF_WG3 + 576000;     // 1536000 sh
// end ~9.9M floats (~40 MB)

typedef float v4f __attribute__((ext_vector_type(4)));
typedef __attribute__((ext_vector_type(4)))  short bf16x4v;
typedef __attribute__((ext_vector_type(8)))  short bf16x8v;
typedef __attribute__((ext_vector_type(16))) float f32x16v;

__device__ __forceinline__ void async_copy16(const float* g, float* l) {
    __builtin_amdgcn_global_load_lds(
        (const __attribute__((address_space(1))) void*)g,
        (__attribute__((address_space(3))) void*)l, 16, 0, 0);
}
__device__ __forceinline__ unsigned short f2bf(float f) {
    unsigned u = __float_as_uint(f);
    return (unsigned short)((u + 0x7FFFu + ((u >> 16) & 1u)) >> 16);
}

__global__ void qmean_kernel(const float* __restrict__ QF, float* __restrict__ out_q,
                             float* __restrict__ scale) {
    int b = blockIdx.x >> 1, c = blockIdx.x & 1;
    float s = 0.f;
    for (int m = threadIdx.x; m < MQn; m += blockDim.x)
        s += QF[(b * MQn + m) * 2 + c];
    __shared__ float sh[256];
    sh[threadIdx.x] = s;
    __syncthreads();
    for (int st = 128; st > 0; st >>= 1) {
        if (threadIdx.x < st) sh[threadIdx.x] += sh[threadIdx.x + st];
        __syncthreads();
    }
    if (threadIdx.x == 0) {
        float mean = sh[0] / (float)MQn;
        out_q[b * 2 + c] = mean;
        if (c == 0) scale[b] = mean;
    }
}

__global__ void mask_pool1_kernel(const float* __restrict__ xf, float* __restrict__ m1,
                                  float* __restrict__ c0) {
    int idx = blockIdx.x * blockDim.x + threadIdx.x;   // 0..65535
    int b = idx >> 15;
    int v = idx & 32767;
    int oz = v >> 10, oy = (v >> 5) & 31, ox = v & 31;
    float cnt = 0.f, mx = 0.f;
    for (int dz = 0; dz < 2; ++dz)
        for (int dy = 0; dy < 2; ++dy)
            for (int dx = 0; dx < 2; ++dx) {
                int z = 2 * oz + dz, y = 2 * oy + dy, x = 2 * ox + dx;
                size_t base = (size_t)b * 4 * D0 * D0 * D0 + ((size_t)z * D0 + y) * D0 + x;
                bool occ = false;
                for (int c = 0; c < 4; ++c)
                    occ = occ || (xf[base + (size_t)c * D0 * D0 * D0] != 0.f);
                if (occ) { cnt += 1.f; mx = 1.f; }
            }
    m1[idx] = mx;
    __shared__ float sh[256];
    sh[threadIdx.x] = cnt;
    __syncthreads();
    for (int st = 128; st > 0; st >>= 1) {
        if (threadIdx.x < st) sh[threadIdx.x] += sh[threadIdx.x + st];
        __syncthreads();
    }
    if (threadIdx.x == 0) atomicAdd(&c0[b], sh[0]);
}

__global__ void pool_kernel(const float* __restrict__ min_, float* __restrict__ mout,
                            float* __restrict__ cacc, int Din) {
    int Do = Din >> 1;
    int per = Do * Do * Do;
    int idx = blockIdx.x * blockDim.x + threadIdx.x;
    int b = idx / per;
    int v = idx % per;
    int oz = v / (Do * Do), oy = (v / Do) % Do, ox = v % Do;
    float s = 0.f, mx = 0.f;
    for (int dz = 0; dz < 2; ++dz)
        for (int dy = 0; dy < 2; ++dy)
            for (int dx = 0; dx < 2; ++dx) {
                float val = min_[(((size_t)b * Din + 2 * oz + dz) * Din + 2 * oy + dy) * Din + 2 * ox + dx];
                s += val;
                mx = fmaxf(mx, val);
            }
    mout[idx] = mx;
    __shared__ float sh[256];
    sh[threadIdx.x] = s;
    __syncthreads();
    for (int st = 128; st > 0; st >>= 1) {
        if (threadIdx.x < st) sh[threadIdx.x] += sh[threadIdx.x + st];
        __syncthreads();
    }
    if (threadIdx.x == 0) atomicAdd(&cacc[b], sh[0]);
}

__global__ void writek_kernel(const float* __restrict__ cnt, float* __restrict__ outk) {
    int i = threadIdx.x;
    if (i < 6) {
        int row = i >> 1, b = i & 1;
        float v = (row == 0) ? cnt[4 + b] : (row == 1 ? cnt[2 + b] : cnt[b]);
        outk[i] = v;
    }
}

// x_feat NCDHW fp32 -> CL bf16 [b][voxel][8] (4 real + 4 zero)
__global__ __launch_bounds__(256) void xcl_kernel(const float* __restrict__ xf,
                                                  unsigned short* __restrict__ xcl) {
    int idx = blockIdx.x * 256 + threadIdx.x;   // b*VOX + sp, VOX=262144
    if (idx >= 2 * 262144) return;
    int b = idx >> 18, sp = idx & 262143;
    bf16x8v o;
#pragma unroll
    for (int ci = 0; ci < 4; ++ci)
        o[ci] = (short)f2bf(xf[((size_t)b * 4 + ci) * 262144 + sp]);
#pragma unroll
    for (int ci = 4; ci < 8; ++ci) o[ci] = 0;
    *(bf16x8v*)&xcl[(size_t)idx * 8] = o;
}

// All 7 weight tensors -> bf16 [cs][nch][tap][n32][kc2][8], zero-guarded ci >= cinR.
constexpr int GS1 = 0,        GE1 = 64000;    // w1  cinP16 cinR4  nch1
constexpr int GS2 = 64000,    GE2 = 192000;   // g1  32 32 1
constexpr int GS3 = 192000,   GE3 = 448000;   // w2  32 32 2
constexpr int GS4 = 448000,   GE4 = 960000;   // g2  64 64 2
constexpr int GS5 = 960000,   GE5 = 1728000;  // w3  64 64 3
constexpr int GS6 = 1728000,  GE6 = 2880000;  // g3  96 96 3
constexpr int GS7 = 2880000,  GE7 = 4416000;  // w4  96 96 4
__global__ __launch_bounds__(256) void mwtrans_all_kernel(
        const float* __restrict__ w1, const float* __restrict__ g1,
        const float* __restrict__ w2, const float* __restrict__ g2,
        const float* __restrict__ w3, const float* __restrict__ g3,
        const float* __restrict__ w4, float* __restrict__ ws) {
    int idx = blockIdx.x * 256 + threadIdx.x;
    if (idx >= GE7) return;
    const float* src; unsigned short* dst; int nchn, cinR, o;
    if (idx < GE1)      { src = w1; dst = (unsigned short*)(ws + OFF_WC1); nchn = 1; cinR = 4;  o = idx - GS1; }
    else if (idx < GE2) { src = g1; dst = (unsigned short*)(ws + OFF_WG1); nchn = 1; cinR = 32; o = idx - GS2; }
    else if (idx < GE3) { src = w2; dst = (unsigned short*)(ws + OFF_WC2); nchn = 2; cinR = 32; o = idx - GS3; }
    else if (idx < GE4) { src = g2; dst = (unsigned short*)(ws + OFF_WG2); nchn = 2; cinR = 64; o = idx - GS4; }
    else if (idx < GE5) { src = w3; dst = (unsigned short*)(ws + OFF_WC3); nchn = 3; cinR = 64; o = idx - GS5; }
    else if (idx < GE6) { src = g3; dst = (unsigned short*)(ws + OFF_WG3); nchn = 3; cinR = 96; o = idx - GS6; }
    else                { src = w4; dst = (unsigned short*)(ws + OFF_WC4); nchn = 4; cinR = 96; o = idx - GS7; }
    int j  = o & 7;
    int kc = (o >> 3) & 1;
    int n  = (o >> 4) & 31;
    int q  = o >> 9;
    int tap = q % 125;
    int q2  = q / 125;
    int nch = q2 % nchn;
    int cs  = q2 / nchn;
    int co = nch * 32 + n;
    int ci = cs * 16 + kc * 8 + j;
    float v = (ci < cinR) ? src[((size_t)co * cinR + ci) * 125 + tap] : 0.f;
    dst[o] = f2bf(v);
}

// ===== stride-2 MFMA conv, parity-class planar LDS =====
// Block = (cs-group, tile). NCSB cs handled internally (NCSB==NCS -> EPI allowed).
template<int DCIN, int COUTt, int DIN, int DOUT, int TZ, int NCSB, bool EPI>
__global__ __launch_bounds__(256) void s2mconv_kernel(
    const unsigned short* __restrict__ in,   // CL bf16 [b][z][y][x][DCIN]
    const unsigned short* __restrict__ wb,   // [cs][nch][tap][n32][kc2][8]
    const float* __restrict__ bias,          // EPI only
    const float* __restrict__ mask,          // EPI only [b][VOX]
    const float* __restrict__ zerow,
    float* __restrict__ tout,                // CL fp32 [b][v][COUTt]
    unsigned short* __restrict__ sqout)      // EPI only: CL bf16 squares
{
    constexpr int NCH = COUTt / 32;
    constexpr int NZW = TZ;
    constexpr int NCW = 4 / NZW;
    constexpr int WCH = (NCH + NCW - 1) / NCW;
    constexpr int UPV = (DCIN == 8) ? 1 : 2 * NCSB;   // 16B channel-parts staged
    constexpr int MZW = (TZ == 4) ? 6 : 4;
    constexpr int MYW = 6, MXW = 10;
    constexpr int HVC = 8 * MZW * MYW * MXW;          // voxel-units per part
    constexpr int NU  = UPV * HVC;
    constexpr int NLOAD = (NU + 255) / 256;
    constexpr int LZR = 2 * TZ + 3;
    constexpr int NTZ = DOUT / TZ, NTY = DOUT / 4, NTX = DOUT / 8;
    constexpr int NT = NTZ * NTY * NTX * Bn;
    constexpr int VOX = DOUT * DOUT * DOUT;
    __shared__ __align__(16) unsigned short lds[NLOAD * 256 * 8];

    int bid = blockIdx.x;
    int tile = bid % NT;
    int cs0 = (bid / NT) * NCSB;
    int r = tile;
    int tx0 = (r % NTX) * 8; r /= NTX;
    int ty0 = (r % NTY) * 4; r /= NTY;
    int tz0 = (r % NTZ) * TZ; int b = r / NTZ;

    int tid = threadIdx.x;
    int iz0 = 2 * tz0 - 2, iy0 = 2 * ty0 - 2, ix0 = 2 * tx0 - 2;
#pragma unroll
    for (int k = 0; k < NLOAD; ++k) {
        int u = tid + k * 256;
        int p = u / HVC, v = u % HVC;
        int mx = v % MXW; int t = v / MXW;
        int my = t % MYW; t /= MYW;
        int mz = t % MZW; int cls = t / MZW;
        int px = cls & 1, py = (cls >> 1) & 1, pz = cls >> 2;
        int lz = 2 * mz + pz, ly = 2 * my + py, lx = 2 * mx + px;
        int gz = iz0 + lz, gy = iy0 + ly, gx = ix0 + lx;
        bool valid = (p < UPV) && (lz < LZR) && (ly < 11) && (lx < 19) &&
                     (unsigned)gz < (unsigned)DIN && (unsigned)gy < (unsigned)DIN &&
                     (unsigned)gx < (unsigned)DIN;
        const unsigned short* g = valid
            ? in + ((((size_t)b * DIN + gz) * DIN + gy) * DIN + gx) * DCIN + cs0 * 16 + p * 8
            : (const unsigned short*)zerow;
        async_copy16((const float*)g, (float*)&lds[(size_t)u * 8]);
    }
    __syncthreads();

    int lane = tid & 63, w = tid >> 6;
    int zz = w % NZW;
    int ch = w / NZW;
    int n = lane & 31, kc = lane >> 5;
    int vy = n >> 3, vx = n & 7;

    f32x16v acc[WCH];
#pragma unroll
    for (int cc = 0; cc < WCH; ++cc)
#pragma unroll
        for (int i = 0; i < 16; ++i) acc[cc][i] = 0.f;

#pragma unroll 1
    for (int kz = 0; kz < 5; ++kz) {
        int mz = zz + (kz >> 1), pz = kz & 1;
#pragma unroll 1
        for (int ky = 0; ky < 5; ++ky) {
            int my = vy + (ky >> 1), py = ky & 1;
#pragma unroll
            for (int kx = 0; kx < 5; ++kx) {
                int px = kx & 1, mx = vx + (kx >> 1);
                int cls = pz * 4 + py * 2 + px;
                int unit = ((cls * MZW + mz) * MYW + my) * MXW + mx;
                int tap = (kz * 5 + ky) * 5 + kx;
#pragma unroll
                for (int l = 0; l < NCSB; ++l) {
                    int uoff = (DCIN == 8) ? (kc ? HVC : unit)        // upper K half = zeros
                                           : (l * 2 + kc) * HVC + unit;
                    bf16x8v dfrag = *(const bf16x8v*)&lds[(size_t)uoff * 8];
                    int cs = cs0 + l;
#pragma unroll
                    for (int cc = 0; cc < WCH; ++cc) {
                        int c = ch * WCH + cc;
                        if (c < NCH) {
                            const unsigned short* wp =
                                wb + (((size_t)(cs * NCH + c) * 125 + tap) << 9) + n * 16 + kc * 8;
                            bf16x8v wfrag = *(const bf16x8v*)wp;
                            acc[cc] = __builtin_amdgcn_mfma_f32_32x32x16_bf16(wfrag, dfrag, acc[cc], 0, 0, 0);
                        }
                    }
                }
            }
        }
    }

    int sp = ((tz0 + zz) * DOUT + (ty0 + vy)) * DOUT + (tx0 + vx);
    size_t base = ((size_t)b * VOX + sp) * COUTt;
    if (EPI) {
        float mval = mask[(size_t)b * VOX + sp];
#pragma unroll
        for (int cc = 0; cc < WCH; ++cc) {
            int c = ch * WCH + cc;
            if (c < NCH) {
#pragma unroll
                for (int g = 0; g < 4; ++g) {
                    int cob = c * 32 + g * 8 + 4 * kc;
                    v4f bi = *(const v4f*)&bias[cob];
                    v4f vv; bf16x4v sv;
#pragma unroll
                    for (int j = 0; j < 4; ++j) {
                        vv[j] = (acc[cc][g * 4 + j] + bi[j]) * mval;
                        sv[j] = (short)f2bf(vv[j] * vv[j]);
                    }
                    *(v4f*)&tout[base + cob] = vv;
                    *(bf16x4v*)&sqout[base + cob] = sv;
                }
            }
        }
    } else {
#pragma unroll
        for (int cc = 0; cc < WCH; ++cc) {
            int c = ch * WCH + cc;
            if (c < NCH) {
#pragma unroll
                for (int rr = 0; rr < 16; ++rr) {
                    int co = c * 32 + (rr & 3) + 8 * (rr >> 2) + 4 * kc;
                    atomicAdd(&tout[base + co], acc[cc][rr]);
                }
            }
        }
    }
}

// ===== fused stride-1 MFMA GDN (full K in-block, inline GDN epilogue) =====
// Block = (co-chunk-group cg, tile). No atomics, no separate epilogue.
template<int CINt, int COUTt, int Dd, int TZ, int YB, int CHB>
__global__ __launch_bounds__(256) void mgdn_kernel(
    const unsigned short* __restrict__ sqin, // CL bf16 squares
    const unsigned short* __restrict__ wb,   // gamma bf16 [cs][nch][tap][n32][kc2][8]
    const float* __restrict__ tbuf,          // CL fp32 t
    const float* __restrict__ beta,
    const float* __restrict__ scale,
    const float* __restrict__ zerow,
    unsigned short* __restrict__ ycl)        // CL bf16 out
{
    constexpr int NCH = COUTt / 32;
    constexpr int NCS = CINt / 16;
    constexpr int UPV = CINt / 8;
    constexpr int LZ = TZ + 4, LYH = YB * 4 + 4, LXH = 12;
    constexpr int HV = LZ * LYH * LXH;
    constexpr int UN = UPV * HV;
    constexpr int NLOAD = (UN + 255) / 256;
    constexpr int NTZ = Dd / TZ, NTY = Dd / (YB * 4), NTX = Dd / 8;
    constexpr int NT = NTZ * NTY * NTX * Bn;
    constexpr int VOX = Dd * Dd * Dd;
    __shared__ __align__(16) unsigned short lds[NLOAD * 256 * 8];

    int bid = blockIdx.x;
    int r = bid % NT;
    int cg = bid / NT;
    int tx0 = (r % NTX) * 8; r /= NTX;
    int ty0 = (r % NTY) * (YB * 4); r /= NTY;
    int tz0 = (r % NTZ) * TZ; int b = r / NTZ;

    int tid = threadIdx.x;
    int iz0 = tz0 - 2, iy0 = ty0 - 2, ix0 = tx0 - 2;
#pragma unroll
    for (int k = 0; k < NLOAD; ++k) {
        int u = tid + k * 256;
        int p = u / HV, v = u % HV;
        int lx = v % LXH; int t = v / LXH;
        int ly = t % LYH, lz = t / LYH;
        int gz = iz0 + lz, gy = iy0 + ly, gx = ix0 + lx;
        bool valid = (p < UPV) &&
                     (unsigned)gz < (unsigned)Dd && (unsigned)gy < (unsigned)Dd &&
                     (unsigned)gx < (unsigned)Dd;
        const unsigned short* g = valid
            ? sqin + ((((size_t)b * Dd + gz) * Dd + gy) * Dd + gx) * CINt + p * 8
            : (const unsigned short*)zerow;
        async_copy16((const float*)g, (float*)&lds[(size_t)u * 8]);
    }
    __syncthreads();

    int lane = tid & 63, w = tid >> 6;
    int zz = (YB == 1) ? w : (w >> 1);
    int yb = (YB == 1) ? 0 : (w & 1);
    int n = lane & 31, kc = lane >> 5;
    int vy = yb * 4 + (n >> 3), vx = n & 7;

    f32x16v acc[CHB];
#pragma unroll
    for (int cc = 0; cc < CHB; ++cc)
#pragma unroll
        for (int i = 0; i < 16; ++i) acc[cc][i] = 0.f;

#pragma unroll 1
    for (int kz = 0; kz < 5; ++kz) {
#pragma unroll 1
        for (int ky = 0; ky < 5; ++ky) {
            int hvrow = ((zz + kz) * LYH + (vy + ky)) * LXH + vx;
#pragma unroll
            for (int kx = 0; kx < 5; ++kx) {
                int tap = (kz * 5 + ky) * 5 + kx;
#pragma unroll
                for (int cs = 0; cs < NCS; ++cs) {
                    bf16x8v dfrag = *(const bf16x8v*)&lds[(size_t)((cs * 2 + kc) * HV + hvrow + kx) * 8];
#pragma unroll
                    for (int cc = 0; cc < CHB; ++cc) {
                        int c = cg * CHB + cc;
                        const unsigned short* wp =
                            wb + (((size_t)(cs * NCH + c) * 125 + tap) << 9) + n * 16 + kc * 8;
                        bf16x8v wfrag = *(const bf16x8v*)wp;
                        acc[cc] = __builtin_amdgcn_mfma_f32_32x32x16_bf16(wfrag, dfrag, acc[cc], 0, 0, 0);
                    }
                }
            }
        }
    }

    int sp = ((tz0 + zz) * Dd + (ty0 + vy)) * Dd + (tx0 + vx);
    size_t base = ((size_t)b * VOX + sp) * COUTt;
    float sc = scale[b];
#pragma unroll
    for (int cc = 0; cc < CHB; ++cc) {
        int c = cg * CHB + cc;
#pragma unroll
        for (int g = 0; g < 4; ++g) {
            int cob = c * 32 + g * 8 + 4 * kc;
            v4f bt = *(const v4f*)&beta[cob];
            v4f tv = *(const v4f*)&tbuf[base + cob];
            bf16x4v yv;
#pragma unroll
            for (int j = 0; j < 4; ++j) {
                float den = bt[j] + acc[cc][g * 4 + j];
                yv[j] = (short)f2bf(tv[j] * rsqrtf(den) * sc);
            }
            *(bf16x4v*)&ycl[base + cob] = yv;
        }
    }
}

// ===== stride-1 MFMA conv with cs/kz block-splitting (GDN3 den + conv4) =====
template<int CINt, int COUTt, int Dd, int TZ, int YB, int CIG, int ZSPL, bool CLD>
__global__ __launch_bounds__(256) void mconv_kernel(
    const unsigned short* __restrict__ in,   // CL bf16 [b][z][y][x][CINt]
    const unsigned short* __restrict__ wb,
    const float* __restrict__ zerow,
    float* __restrict__ dout)                // CLD? CL fp32 : NCDHW fp32 (atomicAdd)
{
    constexpr int NCH = COUTt / 32;
    constexpr int LZ = TZ + 4, LYH = YB * 4 + 4, LXH = 12;
    constexpr int HV = LZ * LYH * LXH;
    constexpr int UN = 2 * HV;
    constexpr int NLOAD = (UN + 255) / 256;
    constexpr int NTZ = Dd / TZ, NTY = Dd / (YB * 4), NTX = Dd / 8;
    constexpr int NT = NTZ * NTY * NTX * Bn;
    constexpr int VOX = Dd * Dd * Dd;
    __shared__ __align__(16) unsigned short lds[NLOAD * 256 * 8];

    int bid = blockIdx.x;
    int tile = bid % NT; int rest = bid / NT;
    int cs = rest % CIG; int zig = rest / CIG;
    int r = tile;
    int tx0 = (r % NTX) * 8; r /= NTX;
    int ty0 = (r % NTY) * (YB * 4); r /= NTY;
    int tz0 = (r % NTZ) * TZ; int b = r / NTZ;

    int tid = threadIdx.x;
    int iz0 = tz0 - 2, iy0 = ty0 - 2, ix0 = tx0 - 2;
#pragma unroll
    for (int k = 0; k < NLOAD; ++k) {
        int u = tid + k * 256;
        int v = u >> 1, half = u & 1;
        int lx = v % LXH; int t = v / LXH;
        int ly = t % LYH, lz = t / LYH;
        int gz = iz0 + lz, gy = iy0 + ly, gx = ix0 + lx;
        bool valid = (v < HV) &&
                     (unsigned)gz < (unsigned)Dd && (unsigned)gy < (unsigned)Dd &&
                     (unsigned)gx < (unsigned)Dd;
        const unsigned short* g = valid
            ? in + ((((size_t)b * Dd + gz) * Dd + gy) * Dd + gx) * CINt + cs * 16 + half * 8
            : (const unsigned short*)zerow;
        async_copy16((const float*)g, (float*)&lds[(size_t)u * 8]);
    }
    __syncthreads();

    int lane = tid & 63, w = tid >> 6;
    int zz = (YB == 1) ? w : (w >> 1);
    int yb = (YB == 1) ? 0 : (w & 1);
    int n = lane & 31, kc = lane >> 5;
    int vy = yb * 4 + (n >> 3), vx = n & 7;

    f32x16v acc[NCH];
#pragma unroll
    for (int c = 0; c < NCH; ++c)
#pragma unroll
        for (int i = 0; i < 16; ++i) acc[c][i] = 0.f;

    int kzlo = (ZSPL == 5) ? zig : 0;
    int kzhi = (ZSPL == 5) ? zig + 1 : 5;
#pragma unroll 1
    for (int kz = kzlo; kz < kzhi; ++kz) {
#pragma unroll 1
        for (int ky = 0; ky < 5; ++ky) {
            int hvrow = ((zz + kz) * LYH + (vy + ky)) * LXH + vx;
#pragma unroll
            for (int kx = 0; kx < 5; ++kx) {
                bf16x8v dfrag = *(const bf16x8v*)&lds[(size_t)(hvrow + kx) * 16 + kc * 8];
                int tap = (kz * 5 + ky) * 5 + kx;
#pragma unroll
                for (int c = 0; c < NCH; ++c) {
                    const unsigned short* wp =
                        wb + (((size_t)(cs * NCH + c) * 125 + tap) << 9) + n * 16 + kc * 8;
                    bf16x8v wfrag = *(const bf16x8v*)wp;
                    acc[c] = __builtin_amdgcn_mfma_f32_32x32x16_bf16(wfrag, dfrag, acc[c], 0, 0, 0);
                }
            }
        }
    }

    int sp = ((tz0 + zz) * Dd + (ty0 + vy)) * Dd + (tx0 + vx);
#pragma unroll
    for (int c = 0; c < NCH; ++c) {
#pragma unroll
        for (int rr = 0; rr < 16; ++rr) {
            int co = c * 32 + (rr & 3) + 8 * (rr >> 2) + 4 * kc;
            if (CLD)
                atomicAdd(&dout[((size_t)b * VOX + sp) * COUTt + co], acc[c][rr]);
            else
                atomicAdd(&dout[(size_t)(b * COUTt + co) * VOX + sp], acc[c][rr]);
        }
    }
}

// CL epilogues (stage 3 only)
template<int C, int DOUT>
__global__ __launch_bounds__(256) void conv_epi_cl_kernel(float* __restrict__ buf,
        const float* __restrict__ bias, const float* __restrict__ mask,
        unsigned short* __restrict__ sq) {
    constexpr int VOX = DOUT * DOUT * DOUT;
    int idx = blockIdx.x * 256 + threadIdx.x;
    if (idx >= Bn * C * VOX) return;
    int co = idx % C;
    int sp = (idx / C) % VOX;
    int b = idx / (C * VOX);
    float v = (buf[idx] + bias[co]) * mask[(size_t)b * VOX + sp];
    buf[idx] = v;
    sq[idx] = f2bf(v * v);
}

template<int C, int DOUT>
__global__ __launch_bounds__(256) void gdn_epi_cl_kernel(const float* __restrict__ t,
        const float* __restrict__ den, const float* __restrict__ beta,
        const float* __restrict__ scale, unsigned short* __restrict__ ycl) {
    constexpr int VOX = DOUT * DOUT * DOUT;
    int idx = blockIdx.x * 256 + threadIdx.x;
    if (idx >= Bn * C * VOX) return;
    int co = idx % C;
    int b = idx / (C * VOX);
    float v = t[idx] * rsqrtf(beta[co] + den[idx]) * scale[b];
    ycl[idx] = f2bf(v);
}

// NCDHW final epilogue (conv4 -> out)
__global__ __launch_bounds__(256) void conv_epi4_kernel(float* __restrict__ buf,
        const float* __restrict__ bias, const float* __restrict__ mask) {
    constexpr int VOX = 512;
    int idx = blockIdx.x * 256 + threadIdx.x;
    if (idx >= Bn * 128 * VOX) return;
    int sp = idx % VOX;
    int co = (idx / VOX) % 128;
    int b = idx / (VOX * 128);
    buf[idx] = (buf[idx] + bias[co]) * mask[b * VOX + sp];
}

extern "C" void kernel_launch(void* const* d_in, const int* in_sizes, int n_in,
                              void* d_out, int out_size, void* d_ws, size_t ws_size,
                              hipStream_t stream) {
    const float* x_feat = (const float*)d_in[0];
    const float* QF     = (const float*)d_in[2];
    const float* w1 = (const float*)d_in[3];  const float* b1 = (const float*)d_in[4];
    const float* w2 = (const float*)d_in[5];  const float* b2 = (const float*)d_in[6];
    const float* w3 = (const float*)d_in[7];  const float* b3 = (const float*)d_in[8];
    const float* w4 = (const float*)d_in[9];  const float* b4 = (const float*)d_in[10];
    const float* beta1 = (const float*)d_in[11]; const float* gamma1 = (const float*)d_in[12];
    const float* beta2 = (const float*)d_in[13]; const float* gamma2 = (const float*)d_in[14];
    const float* beta3 = (const float*)d_in[15]; const float* gamma3 = (const float*)d_in[16];

    float* out = (float*)d_out;
    float* ws = (float*)d_ws;
    float* cnt   = ws + OFF_CNT;
    float* zerow = ws + OFF_ZERO;
    float* scale = ws + OFF_SCALE;
    float* m1 = ws + OFF_M1;  float* m2 = ws + OFF_M2;  float* m3 = ws + OFF_M3;
    float* t1 = ws + OFF_T1CL; float* t2 = ws + OFF_T2CL; float* t3 = ws + OFF_T3CL;
    float* d3 = ws + OFF_D3CL;
    unsigned short* xcl = (unsigned short*)(ws + OFF_XCL);
    unsigned short* y1c = (unsigned short*)(ws + OFF_Y1C);
    unsigned short* sq1 = (unsigned short*)(ws + OFF_SQ1);
    unsigned short* y2c = (unsigned short*)(ws + OFF_Y2C);
    unsigned short* sq2 = (unsigned short*)(ws + OFF_SQ2);
    unsigned short* y3c = (unsigned short*)(ws + OFF_Y3C);
    unsigned short* sq3 = (unsigned short*)(ws + OFF_SQ3);
    unsigned short* wc1 = (unsigned short*)(ws + OFF_WC1);
    unsigned short* wg1 = (unsigned short*)(ws + OFF_WG1);
    unsigned short* wc2 = (unsigned short*)(ws + OFF_WC2);
    unsigned short* wg2 = (unsigned short*)(ws + OFF_WG2);
    unsigned short* wc3 = (unsigned short*)(ws + OFF_WC3);
    unsigned short* wg3 = (unsigned short*)(ws + OFF_WG3);
    unsigned short* wc4 = (unsigned short*)(ws + OFF_WC4);

    hipMemsetAsync(ws, 0, ZERO_END * sizeof(float), stream);       // cnt+zero+t3+d3
    hipMemsetAsync(out + OUT_X, 0, 131072 * sizeof(float), stream);

    qmean_kernel<<<4, 256, 0, stream>>>(QF, out + OUT_Q, scale);
    mask_pool1_kernel<<<256, 256, 0, stream>>>(x_feat, m1, cnt + 0);
    pool_kernel<<<32, 256, 0, stream>>>(m1, m2, cnt + 2, D1);
    pool_kernel<<<4, 256, 0, stream>>>(m2, m3, cnt + 4, D2);
    writek_kernel<<<1, 64, 0, stream>>>(cnt, out + OUT_K);

    xcl_kernel<<<2048, 256, 0, stream>>>(x_feat, xcl);
    mwtrans_all_kernel<<<(GE7 + 255) / 256, 256, 0, stream>>>(
        w1, gamma1, w2, gamma2, w3, gamma3, w4, ws);

    // Stage 1: conv1 s2-MFMA inline epi -> t1,sq1 ; GDN1 fused -> y1c
    s2mconv_kernel<8, 32, 64, 32, 4, 1, true>
        <<<512, 256, 0, stream>>>(xcl, wc1, b1, m1, zerow, t1, sq1);
    mgdn_kernel<32, 32, 32, 4, 1, 1>
        <<<512, 256, 0, stream>>>(sq1, wg1, t1, beta1, scale, zerow, y1c);

    // Stage 2: conv2 s2-MFMA full-K inline epi -> t2,sq2 ; GDN2 fused (co-split x2) -> y2c
    s2mconv_kernel<32, 64, 32, 16, 2, 2, true>
        <<<128, 256, 0, stream>>>(y1c, wc2, b2, m2, zerow, t2, sq2);
    mgdn_kernel<64, 64, 16, 4, 1, 1>
        <<<128, 256, 0, stream>>>(sq2, wg2, t2, beta2, scale, zerow, y2c);

    // Stage 3: conv3 s2-MFMA (cs x4, atomics -> t3) ; epi(+sq3) ; GDN3 MFMA ; epi -> y3c
    s2mconv_kernel<64, 96, 16, 8, 2, 1, false>
        <<<64, 256, 0, stream>>>(y2c, wc3, nullptr, nullptr, zerow, t3, nullptr);
    conv_epi_cl_kernel<96, 8><<<384, 256, 0, stream>>>(t3, b3, m3, sq3);
    mconv_kernel<96, 96, 8, 2, 2, 6, 5, true>
        <<<240, 256, 0, stream>>>(sq3, wg3, zerow, d3);
    gdn_epi_cl_kernel<96, 8><<<384, 256, 0, stream>>>(t3, d3, beta3, scale, y3c);

    // Stage 4: conv4 s1-MFMA -> out NCDHW atomics ; final epilogue
    mconv_kernel<96, 128, 8, 2, 2, 6, 5, false>
        <<<240, 256, 0, stream>>>(y3c, wc4, zerow, out + OUT_X);
    conv_epi4_kernel<<<512, 256, 0, stream>>>(out + OUT_X, b4, m3);
}